// Round 1
// baseline (303.445 us; speedup 1.0000x reference)
//
#include <hip/hip_runtime.h>

typedef _Float16 f16;
typedef __attribute__((ext_vector_type(2))) _Float16 f16x2;
typedef __attribute__((ext_vector_type(8))) _Float16 f16x8;
typedef __attribute__((ext_vector_type(4))) float f32x4;

#define MFMA16(A_, B_, C_) __builtin_amdgcn_mfma_f32_16x16x32_f16(A_, B_, C_, 0, 0, 0)

#define NHEAD 16
#define SEQ 2048
#define DM 1024
#define DK 64
#define NBATCH 2
#define M_TOT (NBATCH * SEQ) /* 4096 */
#define LOG2E 1.44269504088896340736f

// ---------------- mask bit-packing (ballot) ----------------
__global__ void pack_mask_k(const int* __restrict__ mask, unsigned long long* __restrict__ mp, int nwords) {
    int lane = threadIdx.x & 63;
    int gw = (blockIdx.x * blockDim.x + threadIdx.x) >> 6;
    int nw = (gridDim.x * blockDim.x) >> 6;
    for (int w = gw; w < nwords; w += nw) {
        int v = mask[(size_t)w * 64 + lane];
        unsigned long long bits = __ballot(v != 0);
        if (lane == 0) mp[w] = bits;
    }
}

// ---------------- projection GEMM: fp32 X @ fp32 W + b -> f16 per-head [B,H,S,DK] ----------------
#define GBM 128
#define GBN 128
#define GBK 32
#define ASTR (GBK + 8) /* 40 f16 = 80B, 16B-aligned rows for b128 reads */
#define BSTR (GBN + 2) /* 130 f16 -> 65-dword rows: u16 frag reads 2-way (free) */

__global__ __launch_bounds__(256) void gemm_qkv_k(
    const float* __restrict__ Xq, const float* __restrict__ Xk, const float* __restrict__ Xv,
    const float* __restrict__ Wq, const float* __restrict__ Wk, const float* __restrict__ Wv,
    const float* __restrict__ bq, const float* __restrict__ bk, const float* __restrict__ bv,
    f16* __restrict__ Qh, f16* __restrict__ Kh, f16* __restrict__ Vh) {
    __shared__ f16 Al[GBM * ASTR];
    __shared__ f16 Bl[GBK * BSTR];
    const int which = blockIdx.z;
    const float* X = which == 0 ? Xq : (which == 1 ? Xk : Xv);
    const float* W = which == 0 ? Wq : (which == 1 ? Wk : Wv);
    const float* bias = which == 0 ? bq : (which == 1 ? bk : bv);
    f16* OUT = which == 0 ? Qh : (which == 1 ? Kh : Vh);

    const int tid = threadIdx.x;
    const int lane = tid & 63;
    const int wv = tid >> 6;
    const int wr = wv >> 1, wc = wv & 1;
    const int g = lane >> 4, c = lane & 15;
    const int m0 = blockIdx.y * GBM;
    const int n0 = blockIdx.x * GBN;
    const int arow = tid >> 1, ahalf = tid & 1; // A: 128 rows x 2 threads (16 fp32 each)
    const int brow = tid >> 3, bseg = tid & 7;  // B: 32 rows x 8 threads (16 fp32 each)

    f32x4 acc[4][4] = {};

    for (int k0 = 0; k0 < DM; k0 += GBK) {
        const float4* asrc = (const float4*)(X + (size_t)(m0 + arow) * DM + k0 + ahalf * 16);
        float4 a0 = asrc[0], a1 = asrc[1], a2 = asrc[2], a3 = asrc[3];
        const float4* bsrc = (const float4*)(W + (size_t)(k0 + brow) * DM + n0 + bseg * 16);
        float4 b0 = bsrc[0], b1 = bsrc[1], b2 = bsrc[2], b3 = bsrc[3];
        __syncthreads(); // previous tile's frag reads done
        {
            f16x8 h0, h1;
            h0[0] = (f16)a0.x; h0[1] = (f16)a0.y; h0[2] = (f16)a0.z; h0[3] = (f16)a0.w;
            h0[4] = (f16)a1.x; h0[5] = (f16)a1.y; h0[6] = (f16)a1.z; h0[7] = (f16)a1.w;
            h1[0] = (f16)a2.x; h1[1] = (f16)a2.y; h1[2] = (f16)a2.z; h1[3] = (f16)a2.w;
            h1[4] = (f16)a3.x; h1[5] = (f16)a3.y; h1[6] = (f16)a3.z; h1[7] = (f16)a3.w;
            *(f16x8*)&Al[arow * ASTR + ahalf * 16] = h0;
            *(f16x8*)&Al[arow * ASTR + ahalf * 16 + 8] = h1;
            f16* bd = &Bl[brow * BSTR + bseg * 16];
            ((f16x2*)bd)[0] = (f16x2){(f16)b0.x, (f16)b0.y};
            ((f16x2*)bd)[1] = (f16x2){(f16)b0.z, (f16)b0.w};
            ((f16x2*)bd)[2] = (f16x2){(f16)b1.x, (f16)b1.y};
            ((f16x2*)bd)[3] = (f16x2){(f16)b1.z, (f16)b1.w};
            ((f16x2*)bd)[4] = (f16x2){(f16)b2.x, (f16)b2.y};
            ((f16x2*)bd)[5] = (f16x2){(f16)b2.z, (f16)b2.w};
            ((f16x2*)bd)[6] = (f16x2){(f16)b3.x, (f16)b3.y};
            ((f16x2*)bd)[7] = (f16x2){(f16)b3.z, (f16)b3.w};
        }
        __syncthreads();
        f16x8 af[4];
#pragma unroll
        for (int mi = 0; mi < 4; ++mi)
            af[mi] = *(const f16x8*)&Al[(wr * 64 + mi * 16 + c) * ASTR + g * 8];
        f16x8 bf[4];
#pragma unroll
        for (int ni = 0; ni < 4; ++ni) {
#pragma unroll
            for (int j = 0; j < 8; ++j)
                bf[ni][j] = Bl[(g * 8 + j) * BSTR + wc * 64 + ni * 16 + c];
        }
#pragma unroll
        for (int mi = 0; mi < 4; ++mi)
#pragma unroll
            for (int ni = 0; ni < 4; ++ni)
                acc[mi][ni] = MFMA16(af[mi], bf[ni], acc[mi][ni]);
    }
    // epilogue: scatter f16 into [B,H,S,DK]
#pragma unroll
    for (int ni = 0; ni < 4; ++ni) {
        int n = n0 + wc * 64 + ni * 16 + c;
        float bias_n = bias[n];
        int hh = n >> 6, d = n & 63;
#pragma unroll
        for (int mi = 0; mi < 4; ++mi) {
            int mbase = m0 + wr * 64 + mi * 16 + g * 4;
#pragma unroll
            for (int r = 0; r < 4; ++r) {
                int m = mbase + r;
                int bb = m >> 11, s = m & (SEQ - 1);
                OUT[(((size_t)(bb * NHEAD + hh)) * SEQ + s) * DK + d] = (f16)(acc[mi][ni][r] + bias_n);
            }
        }
    }
}

// ---------------- output GEMM: f16 Xo @ fp32 Wo + bo -> fp32 out ----------------
__global__ __launch_bounds__(256) void gemm_out_k(
    const f16* __restrict__ Xo, const float* __restrict__ Wo, const float* __restrict__ bo,
    float* __restrict__ OUT) {
    __shared__ f16 Al[GBM * ASTR];
    __shared__ f16 Bl[GBK * BSTR];
    const int tid = threadIdx.x;
    const int lane = tid & 63;
    const int wv = tid >> 6;
    const int wr = wv >> 1, wc = wv & 1;
    const int g = lane >> 4, c = lane & 15;
    const int m0 = blockIdx.y * GBM;
    const int n0 = blockIdx.x * GBN;
    const int arow = tid >> 1, ahalf = tid & 1;
    const int brow = tid >> 3, bseg = tid & 7;

    f32x4 acc[4][4] = {};

    for (int k0 = 0; k0 < DM; k0 += GBK) {
        const f16x8* asrc = (const f16x8*)(Xo + (size_t)(m0 + arow) * DM + k0 + ahalf * 16);
        f16x8 h0 = asrc[0], h1 = asrc[1];
        const float4* bsrc = (const float4*)(Wo + (size_t)(k0 + brow) * DM + n0 + bseg * 16);
        float4 b0 = bsrc[0], b1 = bsrc[1], b2 = bsrc[2], b3 = bsrc[3];
        __syncthreads();
        *(f16x8*)&Al[arow * ASTR + ahalf * 16] = h0;
        *(f16x8*)&Al[arow * ASTR + ahalf * 16 + 8] = h1;
        {
            f16* bd = &Bl[brow * BSTR + bseg * 16];
            ((f16x2*)bd)[0] = (f16x2){(f16)b0.x, (f16)b0.y};
            ((f16x2*)bd)[1] = (f16x2){(f16)b0.z, (f16)b0.w};
            ((f16x2*)bd)[2] = (f16x2){(f16)b1.x, (f16)b1.y};
            ((f16x2*)bd)[3] = (f16x2){(f16)b1.z, (f16)b1.w};
            ((f16x2*)bd)[4] = (f16x2){(f16)b2.x, (f16)b2.y};
            ((f16x2*)bd)[5] = (f16x2){(f16)b2.z, (f16)b2.w};
            ((f16x2*)bd)[6] = (f16x2){(f16)b3.x, (f16)b3.y};
            ((f16x2*)bd)[7] = (f16x2){(f16)b3.z, (f16)b3.w};
        }
        __syncthreads();
        f16x8 af[4];
#pragma unroll
        for (int mi = 0; mi < 4; ++mi)
            af[mi] = *(const f16x8*)&Al[(wr * 64 + mi * 16 + c) * ASTR + g * 8];
        f16x8 bf[4];
#pragma unroll
        for (int ni = 0; ni < 4; ++ni) {
#pragma unroll
            for (int j = 0; j < 8; ++j)
                bf[ni][j] = Bl[(g * 8 + j) * BSTR + wc * 64 + ni * 16 + c];
        }
#pragma unroll
        for (int mi = 0; mi < 4; ++mi)
#pragma unroll
            for (int ni = 0; ni < 4; ++ni)
                acc[mi][ni] = MFMA16(af[mi], bf[ni], acc[mi][ni]);
    }
#pragma unroll
    for (int ni = 0; ni < 4; ++ni) {
        int n = n0 + wc * 64 + ni * 16 + c;
        float bias_n = bo[n];
#pragma unroll
        for (int mi = 0; mi < 4; ++mi) {
            int mbase = m0 + wr * 64 + mi * 16 + g * 4;
#pragma unroll
            for (int r = 0; r < 4; ++r) {
                int m = mbase + r;
                OUT[(size_t)m * DM + n] = acc[mi][ni][r] + bias_n;
            }
        }
    }
}

// ---------------- flash attention: Q,K,V f16 [B,H,S,DK], bitmask -> Xo f16 [B,S,DM] ----------------
#define KSTR 72
#define VSTR 72
#define PSTR 72

__global__ __launch_bounds__(256) void attn_k(
    const f16* __restrict__ Qh, const f16* __restrict__ Kh, const f16* __restrict__ Vh,
    const unsigned long long* __restrict__ mp, f16* __restrict__ Xo) {
    __shared__ f16 Kl[64 * KSTR];     // K tile [key][d]
    __shared__ f16 Vt[64 * VSTR];     // V tile transposed [d][key]
    __shared__ f16 Pl[4][16 * PSTR];  // per-wave P round-trip

    const int tid = threadIdx.x, lane = tid & 63, wv = tid >> 6;
    const int g = lane >> 4, c = lane & 15;
    const int qt = blockIdx.x, hh = blockIdx.y, b = blockIdx.z;

    const size_t headoff = ((size_t)(b * NHEAD + hh)) * SEQ * DK;
    const f16* Qb = Qh + headoff;
    const f16* Kb = Kh + headoff;
    const f16* Vb = Vh + headoff;

    // Q A-fragments held in registers for the whole block
    const int qfrow = qt * 64 + wv * 16 + c;
    f16x8 aq0 = *(const f16x8*)&Qb[(size_t)qfrow * DK + g * 8];
    f16x8 aq1 = *(const f16x8*)&Qb[(size_t)qfrow * DK + 32 + g * 8];

    f32x4 acc[4] = {};
    float m_run[4], l_run[4];
#pragma unroll
    for (int r = 0; r < 4; ++r) { m_run[r] = -3.0e38f; l_run[r] = 0.f; }

    // this lane's 4 q-rows start at qt*64 + wv*16 + g*4
    const unsigned long long* mrow = mp + ((size_t)b * SEQ + qt * 64 + wv * 16 + g * 4) * (SEQ / 64);

    const int krow = tid >> 2, kseg = tid & 3; // staging: 64 rows x 4 threads x 16 f16

    for (int kt = 0; kt < SEQ / 64; ++kt) {
        const f16x8* ksrc = (const f16x8*)&Kb[((size_t)(kt * 64 + krow)) * DK + kseg * 16];
        f16x8 kv0 = ksrc[0], kv1 = ksrc[1];
        const f16x8* vsrc = (const f16x8*)&Vb[((size_t)(kt * 64 + krow)) * DK + kseg * 16];
        f16x8 vv0 = vsrc[0], vv1 = vsrc[1];
        __syncthreads(); // previous tile consumed
        *(f16x8*)&Kl[krow * KSTR + kseg * 16] = kv0;
        *(f16x8*)&Kl[krow * KSTR + kseg * 16 + 8] = kv1;
#pragma unroll
        for (int i = 0; i < 8; ++i) {
            Vt[(kseg * 16 + i) * VSTR + krow] = vv0[i];
            Vt[(kseg * 16 + 8 + i) * VSTR + krow] = vv1[i];
        }
        __syncthreads();

        // QK^T : sc[nk] = 16x16 tile, keys nk*16..+15
        f32x4 sc[4];
#pragma unroll
        for (int nk = 0; nk < 4; ++nk) {
            f16x8 bk0 = *(const f16x8*)&Kl[(nk * 16 + c) * KSTR + g * 8];
            f16x8 bk1 = *(const f16x8*)&Kl[(nk * 16 + c) * KSTR + 32 + g * 8];
            f32x4 z = {};
            z = MFMA16(aq0, bk0, z);
            z = MFMA16(aq1, bk1, z);
            sc[nk] = z;
        }

        unsigned long long wbits[4];
#pragma unroll
        for (int r = 0; r < 4; ++r) wbits[r] = mrow[r * (SEQ / 64) + kt];

        float pm[4] = {-3.0e38f, -3.0e38f, -3.0e38f, -3.0e38f};
#pragma unroll
        for (int nk = 0; nk < 4; ++nk)
#pragma unroll
            for (int r = 0; r < 4; ++r) {
                float sv = sc[nk][r] * 0.125f; // 1/sqrt(DK)
                bool keep = (wbits[r] >> (nk * 16 + c)) & 1ull;
                sv = keep ? sv : -1.0e9f;
                sc[nk][r] = sv;
                pm[r] = fmaxf(pm[r], sv);
            }
        // row-max across the 16 lanes holding this row
#pragma unroll
        for (int off = 1; off < 16; off <<= 1)
#pragma unroll
            for (int r = 0; r < 4; ++r)
                pm[r] = fmaxf(pm[r], __shfl_xor(pm[r], off, 64));

        float corr[4];
#pragma unroll
        for (int r = 0; r < 4; ++r) {
            float mn = fmaxf(m_run[r], pm[r]);
            corr[r] = exp2f((m_run[r] - mn) * LOG2E);
            m_run[r] = mn;
        }
        float ps[4] = {0.f, 0.f, 0.f, 0.f};
#pragma unroll
        for (int nk = 0; nk < 4; ++nk)
#pragma unroll
            for (int r = 0; r < 4; ++r) {
                float p = exp2f((sc[nk][r] - m_run[r]) * LOG2E);
                sc[nk][r] = p;
                ps[r] += p;
            }
#pragma unroll
        for (int off = 1; off < 16; off <<= 1)
#pragma unroll
            for (int r = 0; r < 4; ++r)
                ps[r] += __shfl_xor(ps[r], off, 64);
#pragma unroll
        for (int r = 0; r < 4; ++r) l_run[r] = l_run[r] * corr[r] + ps[r];
#pragma unroll
        for (int ni = 0; ni < 4; ++ni)
#pragma unroll
            for (int r = 0; r < 4; ++r) acc[ni][r] *= corr[r];

        // P (D-layout) -> LDS -> A-layout fragments
#pragma unroll
        for (int nk = 0; nk < 4; ++nk)
#pragma unroll
            for (int r = 0; r < 4; ++r)
                Pl[wv][(g * 4 + r) * PSTR + nk * 16 + c] = (f16)sc[nk][r];

        f16x8 ap0 = *(const f16x8*)&Pl[wv][c * PSTR + g * 8];
        f16x8 ap1 = *(const f16x8*)&Pl[wv][c * PSTR + 32 + g * 8];
#pragma unroll
        for (int ni = 0; ni < 4; ++ni) {
            f16x8 bv0 = *(const f16x8*)&Vt[(ni * 16 + c) * VSTR + g * 8];
            f16x8 bv1 = *(const f16x8*)&Vt[(ni * 16 + c) * VSTR + 32 + g * 8];
            acc[ni] = MFMA16(ap0, bv0, acc[ni]);
            acc[ni] = MFMA16(ap1, bv1, acc[ni]);
        }
    }

#pragma unroll
    for (int r = 0; r < 4; ++r) {
        float inv = 1.0f / l_run[r];
        int q = qt * 64 + wv * 16 + g * 4 + r;
#pragma unroll
        for (int ni = 0; ni < 4; ++ni)
            Xo[((size_t)(b * SEQ + q)) * DM + hh * DK + ni * 16 + c] = (f16)(acc[ni][r] * inv);
    }
}

extern "C" void kernel_launch(void* const* d_in, const int* in_sizes, int n_in,
                              void* d_out, int out_size, void* d_ws, size_t ws_size,
                              hipStream_t stream) {
    const float* query = (const float*)d_in[0];
    const float* key_ = (const float*)d_in[1];
    const float* value = (const float*)d_in[2];
    const int* mask = (const int*)d_in[3];
    const float* Wq = (const float*)d_in[4];
    const float* bq = (const float*)d_in[5];
    const float* Wk = (const float*)d_in[6];
    const float* bk = (const float*)d_in[7];
    const float* Wv = (const float*)d_in[8];
    const float* bv = (const float*)d_in[9];
    const float* Wo = (const float*)d_in[10];
    const float* bo = (const float*)d_in[11];
    float* out = (float*)d_out;

    // workspace layout: Qh | Kh | Vh | Xo | packed-mask   (total ~34.6 MB)
    char* ws = (char*)d_ws;
    const size_t headsz = (size_t)NBATCH * NHEAD * SEQ * DK * sizeof(f16); // 8 MiB
    f16* Qh = (f16*)(ws);
    f16* Kh = (f16*)(ws + headsz);
    f16* Vh = (f16*)(ws + 2 * headsz);
    f16* Xo = (f16*)(ws + 3 * headsz);
    unsigned long long* mp = (unsigned long long*)(ws + 4 * headsz);

    int nwords = NBATCH * SEQ * (SEQ / 64);
    hipLaunchKernelGGL(pack_mask_k, dim3(512), dim3(256), 0, stream, mask, mp, nwords);
    hipLaunchKernelGGL(gemm_qkv_k, dim3(DM / GBN, M_TOT / GBM, 3), dim3(256), 0, stream,
                       query, key_, value, Wq, Wk, Wv, bq, bk, bv, Qh, Kh, Vh);
    hipLaunchKernelGGL(attn_k, dim3(SEQ / 64, NHEAD, NBATCH), dim3(256), 0, stream, Qh, Kh, Vh, mp, Xo);
    hipLaunchKernelGGL(gemm_out_k, dim3(DM / GBN, M_TOT / GBM), dim3(256), 0, stream, Xo, Wo, bo, out);
}

// Round 2
// 255.378 us; speedup vs baseline: 1.1882x; 1.1882x over previous
//
#include <hip/hip_runtime.h>

typedef _Float16 f16;
typedef __attribute__((ext_vector_type(2))) _Float16 f16x2;
typedef __attribute__((ext_vector_type(4))) _Float16 f16x4;
typedef __attribute__((ext_vector_type(8))) _Float16 f16x8;
typedef __attribute__((ext_vector_type(4))) float f32x4;

#define MFMA16(A_, B_, C_) __builtin_amdgcn_mfma_f32_16x16x32_f16(A_, B_, C_, 0, 0, 0)

#define NHEAD 16
#define SEQ 2048
#define DM 1024
#define DK 64
#define NBATCH 2
#define M_TOT (NBATCH * SEQ) /* 4096 */
#define LOG2E 1.44269504088896340736f

// ---------------- mask bit-packing (ballot) ----------------
__global__ void pack_mask_k(const int* __restrict__ mask, unsigned long long* __restrict__ mp, int nwords) {
    int lane = threadIdx.x & 63;
    int gw = (blockIdx.x * blockDim.x + threadIdx.x) >> 6;
    int nw = (gridDim.x * blockDim.x) >> 6;
    for (int w = gw; w < nwords; w += nw) {
        int v = mask[(size_t)w * 64 + lane];
        unsigned long long bits = __ballot(v != 0);
        if (lane == 0) mp[w] = bits;
    }
}

// ---------------- projection GEMM: fp32 X @ fp32 W + b -> f16 per-head [B,H,S,DK] ----------------
#define GBM 128
#define GBN 128
#define GBK 32
#define ASTR (GBK + 8) /* 40 f16 = 80B, 16B-aligned rows for b128 reads */
#define BSTR (GBN + 2) /* 130 f16 -> 65-dword rows: u16 frag reads 2-way (free) */

__global__ __launch_bounds__(256) void gemm_qkv_k(
    const float* __restrict__ Xq, const float* __restrict__ Xk, const float* __restrict__ Xv,
    const float* __restrict__ Wq, const float* __restrict__ Wk, const float* __restrict__ Wv,
    const float* __restrict__ bq, const float* __restrict__ bk, const float* __restrict__ bv,
    f16* __restrict__ Qh, f16* __restrict__ Kh, f16* __restrict__ Vh) {
    __shared__ f16 Al[GBM * ASTR];
    __shared__ f16 Bl[GBK * BSTR];
    const int which = blockIdx.z;
    const float* X = which == 0 ? Xq : (which == 1 ? Xk : Xv);
    const float* W = which == 0 ? Wq : (which == 1 ? Wk : Wv);
    const float* bias = which == 0 ? bq : (which == 1 ? bk : bv);
    f16* OUT = which == 0 ? Qh : (which == 1 ? Kh : Vh);

    const int tid = threadIdx.x;
    const int lane = tid & 63;
    const int wv = tid >> 6;
    const int wr = wv >> 1, wc = wv & 1;
    const int g = lane >> 4, c = lane & 15;
    const int m0 = blockIdx.y * GBM;
    const int n0 = blockIdx.x * GBN;
    const int arow = tid >> 1, ahalf = tid & 1; // A: 128 rows x 2 threads (16 fp32 each)
    const int brow = tid >> 3, bseg = tid & 7;  // B: 32 rows x 8 threads (16 fp32 each)

    f32x4 acc[4][4] = {};

    for (int k0 = 0; k0 < DM; k0 += GBK) {
        const float4* asrc = (const float4*)(X + (size_t)(m0 + arow) * DM + k0 + ahalf * 16);
        float4 a0 = asrc[0], a1 = asrc[1], a2 = asrc[2], a3 = asrc[3];
        const float4* bsrc = (const float4*)(W + (size_t)(k0 + brow) * DM + n0 + bseg * 16);
        float4 b0 = bsrc[0], b1 = bsrc[1], b2 = bsrc[2], b3 = bsrc[3];
        __syncthreads(); // previous tile's frag reads done
        {
            f16x8 h0, h1;
            h0[0] = (f16)a0.x; h0[1] = (f16)a0.y; h0[2] = (f16)a0.z; h0[3] = (f16)a0.w;
            h0[4] = (f16)a1.x; h0[5] = (f16)a1.y; h0[6] = (f16)a1.z; h0[7] = (f16)a1.w;
            h1[0] = (f16)a2.x; h1[1] = (f16)a2.y; h1[2] = (f16)a2.z; h1[3] = (f16)a2.w;
            h1[4] = (f16)a3.x; h1[5] = (f16)a3.y; h1[6] = (f16)a3.z; h1[7] = (f16)a3.w;
            *(f16x8*)&Al[arow * ASTR + ahalf * 16] = h0;
            *(f16x8*)&Al[arow * ASTR + ahalf * 16 + 8] = h1;
            f16* bd = &Bl[brow * BSTR + bseg * 16];
            ((f16x2*)bd)[0] = (f16x2){(f16)b0.x, (f16)b0.y};
            ((f16x2*)bd)[1] = (f16x2){(f16)b0.z, (f16)b0.w};
            ((f16x2*)bd)[2] = (f16x2){(f16)b1.x, (f16)b1.y};
            ((f16x2*)bd)[3] = (f16x2){(f16)b1.z, (f16)b1.w};
            ((f16x2*)bd)[4] = (f16x2){(f16)b2.x, (f16)b2.y};
            ((f16x2*)bd)[5] = (f16x2){(f16)b2.z, (f16)b2.w};
            ((f16x2*)bd)[6] = (f16x2){(f16)b3.x, (f16)b3.y};
            ((f16x2*)bd)[7] = (f16x2){(f16)b3.z, (f16)b3.w};
        }
        __syncthreads();
        f16x8 af[4];
#pragma unroll
        for (int mi = 0; mi < 4; ++mi)
            af[mi] = *(const f16x8*)&Al[(wr * 64 + mi * 16 + c) * ASTR + g * 8];
        f16x8 bf[4];
#pragma unroll
        for (int ni = 0; ni < 4; ++ni) {
#pragma unroll
            for (int j = 0; j < 8; ++j)
                bf[ni][j] = Bl[(g * 8 + j) * BSTR + wc * 64 + ni * 16 + c];
        }
#pragma unroll
        for (int mi = 0; mi < 4; ++mi)
#pragma unroll
            for (int ni = 0; ni < 4; ++ni)
                acc[mi][ni] = MFMA16(af[mi], bf[ni], acc[mi][ni]);
    }
    // epilogue: scatter f16 into [B,H,S,DK]
#pragma unroll
    for (int ni = 0; ni < 4; ++ni) {
        int n = n0 + wc * 64 + ni * 16 + c;
        float bias_n = bias[n];
        int hh = n >> 6, d = n & 63;
#pragma unroll
        for (int mi = 0; mi < 4; ++mi) {
            int mbase = m0 + wr * 64 + mi * 16 + g * 4;
#pragma unroll
            for (int r = 0; r < 4; ++r) {
                int m = mbase + r;
                int bb = m >> 11, s = m & (SEQ - 1);
                OUT[(((size_t)(bb * NHEAD + hh)) * SEQ + s) * DK + d] = (f16)(acc[mi][ni][r] + bias_n);
            }
        }
    }
}

// ---------------- output GEMM: f16 Xo @ fp32 Wo + bo -> fp32 out ----------------
__global__ __launch_bounds__(256) void gemm_out_k(
    const f16* __restrict__ Xo, const float* __restrict__ Wo, const float* __restrict__ bo,
    float* __restrict__ OUT) {
    __shared__ f16 Al[GBM * ASTR];
    __shared__ f16 Bl[GBK * BSTR];
    const int tid = threadIdx.x;
    const int lane = tid & 63;
    const int wv = tid >> 6;
    const int wr = wv >> 1, wc = wv & 1;
    const int g = lane >> 4, c = lane & 15;
    const int m0 = blockIdx.y * GBM;
    const int n0 = blockIdx.x * GBN;
    const int arow = tid >> 1, ahalf = tid & 1;
    const int brow = tid >> 3, bseg = tid & 7;

    f32x4 acc[4][4] = {};

    for (int k0 = 0; k0 < DM; k0 += GBK) {
        const f16x8* asrc = (const f16x8*)(Xo + (size_t)(m0 + arow) * DM + k0 + ahalf * 16);
        f16x8 h0 = asrc[0], h1 = asrc[1];
        const float4* bsrc = (const float4*)(Wo + (size_t)(k0 + brow) * DM + n0 + bseg * 16);
        float4 b0 = bsrc[0], b1 = bsrc[1], b2 = bsrc[2], b3 = bsrc[3];
        __syncthreads();
        *(f16x8*)&Al[arow * ASTR + ahalf * 16] = h0;
        *(f16x8*)&Al[arow * ASTR + ahalf * 16 + 8] = h1;
        {
            f16* bd = &Bl[brow * BSTR + bseg * 16];
            ((f16x2*)bd)[0] = (f16x2){(f16)b0.x, (f16)b0.y};
            ((f16x2*)bd)[1] = (f16x2){(f16)b0.z, (f16)b0.w};
            ((f16x2*)bd)[2] = (f16x2){(f16)b1.x, (f16)b1.y};
            ((f16x2*)bd)[3] = (f16x2){(f16)b1.z, (f16)b1.w};
            ((f16x2*)bd)[4] = (f16x2){(f16)b2.x, (f16)b2.y};
            ((f16x2*)bd)[5] = (f16x2){(f16)b2.z, (f16)b2.w};
            ((f16x2*)bd)[6] = (f16x2){(f16)b3.x, (f16)b3.y};
            ((f16x2*)bd)[7] = (f16x2){(f16)b3.z, (f16)b3.w};
        }
        __syncthreads();
        f16x8 af[4];
#pragma unroll
        for (int mi = 0; mi < 4; ++mi)
            af[mi] = *(const f16x8*)&Al[(wr * 64 + mi * 16 + c) * ASTR + g * 8];
        f16x8 bf[4];
#pragma unroll
        for (int ni = 0; ni < 4; ++ni) {
#pragma unroll
            for (int j = 0; j < 8; ++j)
                bf[ni][j] = Bl[(g * 8 + j) * BSTR + wc * 64 + ni * 16 + c];
        }
#pragma unroll
        for (int mi = 0; mi < 4; ++mi)
#pragma unroll
            for (int ni = 0; ni < 4; ++ni)
                acc[mi][ni] = MFMA16(af[mi], bf[ni], acc[mi][ni]);
    }
#pragma unroll
    for (int ni = 0; ni < 4; ++ni) {
        int n = n0 + wc * 64 + ni * 16 + c;
        float bias_n = bo[n];
#pragma unroll
        for (int mi = 0; mi < 4; ++mi) {
            int mbase = m0 + wr * 64 + mi * 16 + g * 4;
#pragma unroll
            for (int r = 0; r < 4; ++r) {
                int m = mbase + r;
                OUT[(size_t)m * DM + n] = acc[mi][ni][r] + bias_n;
            }
        }
    }
}

// ---------------- flash attention (swapped-operand), QBLK=128 ----------------
// S^T = K.Q^T  (A=K frag, B=Q frag) -> D-layout: col=q=lane&15, row=key
// O^T = V^T.P^T (A=V^T frag from transposed-V LDS, B=P^T frag from per-wave P buffer)
// LDS tiles are linear [64 rows][64 cols] f16 with 16B-chunk XOR swizzle:
#define SW(r, z) (((z) ^ ((r) & 7) ^ (((r) >> 3) & 7)))
#define QBLK 128
#define CSC 0.18033688011112042f /* 0.125 * log2(e): scores scaled into log2 domain */

__global__ __launch_bounds__(256, 2) void attn_k(
    const f16* __restrict__ Qh, const f16* __restrict__ Kh, const f16* __restrict__ Vh,
    const unsigned long long* __restrict__ mp, f16* __restrict__ Xo) {
    __shared__ f16 Klds[2][4096]; // [key][d], swizzled chunks
    __shared__ f16 Vt[2][4096];   // [d][key], swizzled chunks
    __shared__ f16 Plds[4][16 * 72]; // per-wave P[qlocal][key], 72-f16 stride

    const int tid = threadIdx.x, lane = tid & 63, wv = tid >> 6;
    const int g = lane >> 4, c = lane & 15;
    const int qt = blockIdx.x, hh = blockIdx.y, b = blockIdx.z;
    const size_t headoff = ((size_t)(b * NHEAD + hh)) * SEQ * DK;
    const f16* Qb = Qh + headoff;
    const f16* Kb = Kh + headoff;
    const f16* Vb = Vh + headoff;

    // Q B-frags (lane holds Q[qrow][d=ks*32+g*8..+7]), held all kernel
    int qrow[2];
    f16x8 bq[2][2];
#pragma unroll
    for (int qg = 0; qg < 2; ++qg) {
        qrow[qg] = qt * QBLK + wv * 32 + qg * 16 + c;
        bq[qg][0] = *(const f16x8*)&Qb[(size_t)qrow[qg] * DK + g * 8];
        bq[qg][1] = *(const f16x8*)&Qb[(size_t)qrow[qg] * DK + 32 + g * 8];
    }

    f32x4 acc[2][4] = {}; // O^T per qg, per nd-tile
    float m_run[2] = {-3e38f, -3e38f}, l_run[2] = {0.f, 0.f};

    const int krow = tid >> 2, kseg = tid & 3; // staging: 64 rows x 4 threads x 16 f16

    f16x8 ck0, ck1, cv0, cv1;
    { // load tile 0
        const f16x8* ks_ = (const f16x8*)&Kb[(size_t)krow * DK + kseg * 16];
        ck0 = ks_[0]; ck1 = ks_[1];
        const f16x8* vs_ = (const f16x8*)&Vb[(size_t)krow * DK + kseg * 16];
        cv0 = vs_[0]; cv1 = vs_[1];
    }
    // write tile 0 into buf 0
    *(f16x8*)&Klds[0][krow * 64 + SW(krow, kseg * 2) * 8] = ck0;
    *(f16x8*)&Klds[0][krow * 64 + SW(krow, kseg * 2 + 1) * 8] = ck1;
#pragma unroll
    for (int i = 0; i < 8; ++i) {
        int d0 = kseg * 16 + i, d1 = d0 + 8;
        Vt[0][d0 * 64 + SW(d0, krow >> 3) * 8 + (krow & 7)] = cv0[i];
        Vt[0][d1 * 64 + SW(d1, krow >> 3) * 8 + (krow & 7)] = cv1[i];
    }
    { // load tile 1
        const f16x8* ks_ = (const f16x8*)&Kb[(size_t)(64 + krow) * DK + kseg * 16];
        ck0 = ks_[0]; ck1 = ks_[1];
        const f16x8* vs_ = (const f16x8*)&Vb[(size_t)(64 + krow) * DK + kseg * 16];
        cv0 = vs_[0]; cv1 = vs_[1];
    }

    int p = 0;
    for (int kt = 0; kt < SEQ / 64; ++kt) {
        __syncthreads(); // tile kt staged in buf p by all waves (pre-barrier drain)

        // fragment reads from buf p
        f16x8 ak[4][2], av[4][2];
#pragma unroll
        for (int nk = 0; nk < 4; ++nk) {
            int row = nk * 16 + c;
#pragma unroll
            for (int ks = 0; ks < 2; ++ks)
                ak[nk][ks] = *(const f16x8*)&Klds[p][row * 64 + SW(row, ks * 4 + g) * 8];
        }
#pragma unroll
        for (int nd = 0; nd < 4; ++nd) {
            int row = nd * 16 + c;
#pragma unroll
            for (int ks = 0; ks < 2; ++ks)
                av[nd][ks] = *(const f16x8*)&Vt[p][row * 64 + SW(row, ks * 4 + g) * 8];
        }

        // stage tile kt+1 into buf p^1 (overlaps compute; drained at next barrier)
        if (kt + 1 < SEQ / 64) {
            *(f16x8*)&Klds[p ^ 1][krow * 64 + SW(krow, kseg * 2) * 8] = ck0;
            *(f16x8*)&Klds[p ^ 1][krow * 64 + SW(krow, kseg * 2 + 1) * 8] = ck1;
#pragma unroll
            for (int i = 0; i < 8; ++i) {
                int d0 = kseg * 16 + i, d1 = d0 + 8;
                Vt[p ^ 1][d0 * 64 + SW(d0, krow >> 3) * 8 + (krow & 7)] = cv0[i];
                Vt[p ^ 1][d1 * 64 + SW(d1, krow >> 3) * 8 + (krow & 7)] = cv1[i];
            }
            if (kt + 2 < SEQ / 64) {
                const f16x8* ks_ = (const f16x8*)&Kb[(size_t)((kt + 2) * 64 + krow) * DK + kseg * 16];
                ck0 = ks_[0]; ck1 = ks_[1];
                const f16x8* vs_ = (const f16x8*)&Vb[(size_t)((kt + 2) * 64 + krow) * DK + kseg * 16];
                cv0 = vs_[0]; cv1 = vs_[1];
            }
        }

#pragma unroll
        for (int qg = 0; qg < 2; ++qg) {
            // S^T tiles: keys nk*16 + g*4 + r, q = c
            f32x4 sc[4];
#pragma unroll
            for (int nk = 0; nk < 4; ++nk) {
                f32x4 z = {};
                z = MFMA16(ak[nk][0], bq[qg][0], z);
                z = MFMA16(ak[nk][1], bq[qg][1], z);
                sc[nk] = z;
            }
            unsigned long long wq = mp[((size_t)b * SEQ + qrow[qg]) * (SEQ / 64) + kt] >> (g * 4);
            float pm = -3e38f;
#pragma unroll
            for (int nk = 0; nk < 4; ++nk)
#pragma unroll
                for (int r = 0; r < 4; ++r) {
                    float sv = ((wq >> (nk * 16 + r)) & 1ull) ? sc[nk][r] * CSC : -1.0e9f;
                    sc[nk][r] = sv;
                    pm = fmaxf(pm, sv);
                }
            // tile max across the 4 g-lanes holding this q
            pm = fmaxf(pm, __shfl_xor(pm, 16));
            pm = fmaxf(pm, __shfl_xor(pm, 32));
            float mn = fmaxf(m_run[qg], pm);
            float corr = exp2f(m_run[qg] - mn);
            m_run[qg] = mn;
            float ps = 0.f;
#pragma unroll
            for (int nk = 0; nk < 4; ++nk)
#pragma unroll
                for (int r = 0; r < 4; ++r) {
                    float pp = exp2f(sc[nk][r] - mn);
                    sc[nk][r] = pp;
                    ps += pp;
                }
            ps += __shfl_xor(ps, 16);
            ps += __shfl_xor(ps, 32);
            l_run[qg] = l_run[qg] * corr + ps;
#pragma unroll
            for (int nd = 0; nd < 4; ++nd)
#pragma unroll
                for (int r = 0; r < 4; ++r) acc[qg][nd][r] *= corr;

            // P roundtrip: write P[q=c][key], read P^T B-frags (in-order LDS per wave)
#pragma unroll
            for (int nk = 0; nk < 4; ++nk)
#pragma unroll
                for (int r2 = 0; r2 < 2; ++r2) {
                    f16x2 pw = {(f16)sc[nk][r2 * 2], (f16)sc[nk][r2 * 2 + 1]};
                    *(f16x2*)&Plds[wv][c * 72 + nk * 16 + g * 4 + r2 * 2] = pw;
                }
            f16x8 pb0 = *(const f16x8*)&Plds[wv][c * 72 + g * 8];
            f16x8 pb1 = *(const f16x8*)&Plds[wv][c * 72 + 32 + g * 8];
#pragma unroll
            for (int nd = 0; nd < 4; ++nd) {
                acc[qg][nd] = MFMA16(av[nd][0], pb0, acc[qg][nd]);
                acc[qg][nd] = MFMA16(av[nd][1], pb1, acc[qg][nd]);
            }
        }
        p ^= 1;
    }

    // epilogue: O^T D-layout -> Xo[q][hh*64 + d], packed 8B stores
#pragma unroll
    for (int qg = 0; qg < 2; ++qg) {
        float inv = 1.0f / l_run[qg];
#pragma unroll
        for (int nd = 0; nd < 4; ++nd) {
            f16x4 o;
#pragma unroll
            for (int r = 0; r < 4; ++r) o[r] = (f16)(acc[qg][nd][r] * inv);
            *(f16x4*)&Xo[((size_t)(b * SEQ) + qrow[qg]) * DM + hh * DK + nd * 16 + g * 4] = o;
        }
    }
}

extern "C" void kernel_launch(void* const* d_in, const int* in_sizes, int n_in,
                              void* d_out, int out_size, void* d_ws, size_t ws_size,
                              hipStream_t stream) {
    const float* query = (const float*)d_in[0];
    const float* key_ = (const float*)d_in[1];
    const float* value = (const float*)d_in[2];
    const int* mask = (const int*)d_in[3];
    const float* Wq = (const float*)d_in[4];
    const float* bq = (const float*)d_in[5];
    const float* Wk = (const float*)d_in[6];
    const float* bk = (const float*)d_in[7];
    const float* Wv = (const float*)d_in[8];
    const float* bv = (const float*)d_in[9];
    const float* Wo = (const float*)d_in[10];
    const float* bo = (const float*)d_in[11];
    float* out = (float*)d_out;

    // workspace layout: Qh | Kh | Vh | Xo | packed-mask   (total ~34.6 MB)
    char* ws = (char*)d_ws;
    const size_t headsz = (size_t)NBATCH * NHEAD * SEQ * DK * sizeof(f16); // 8 MiB
    f16* Qh = (f16*)(ws);
    f16* Kh = (f16*)(ws + headsz);
    f16* Vh = (f16*)(ws + 2 * headsz);
    f16* Xo = (f16*)(ws + 3 * headsz);
    unsigned long long* mp = (unsigned long long*)(ws + 4 * headsz);

    int nwords = NBATCH * SEQ * (SEQ / 64);
    hipLaunchKernelGGL(pack_mask_k, dim3(512), dim3(256), 0, stream, mask, mp, nwords);
    hipLaunchKernelGGL(gemm_qkv_k, dim3(DM / GBN, M_TOT / GBM, 3), dim3(256), 0, stream,
                       query, key_, value, Wq, Wk, Wv, bq, bk, bv, Qh, Kh, Vh);
    hipLaunchKernelGGL(attn_k, dim3(SEQ / QBLK, NHEAD, NBATCH), dim3(256), 0, stream, Qh, Kh, Vh, mp, Xo);
    hipLaunchKernelGGL(gemm_out_k, dim3(DM / GBN, M_TOT / GBM), dim3(256), 0, stream, Xo, Wo, bo, out);
}

// Round 3
// 208.496 us; speedup vs baseline: 1.4554x; 1.2249x over previous
//
#include <hip/hip_runtime.h>

typedef _Float16 f16;
typedef __attribute__((ext_vector_type(2))) _Float16 f16x2;
typedef __attribute__((ext_vector_type(4))) _Float16 f16x4;
typedef __attribute__((ext_vector_type(8))) _Float16 f16x8;
typedef __attribute__((ext_vector_type(4))) float f32x4;

#define MFMA16(A_, B_, C_) __builtin_amdgcn_mfma_f32_16x16x32_f16(A_, B_, C_, 0, 0, 0)

#define NHEAD 16
#define SEQ 2048
#define DM 1024
#define DK 64
#define NBATCH 2
#define M_TOT (NBATCH * SEQ) /* 4096 */

// direct-to-LDS 16B staging (per-lane global addr, linear LDS dest)
#define GLDS(gp, lp)                                                                     \
    __builtin_amdgcn_global_load_lds((const __attribute__((address_space(1))) void*)(gp), \
                                     (__attribute__((address_space(3))) void*)(lp), 16, 0, 0)

// ---------------- mask bit-packing (ballot) ----------------
__global__ void pack_mask_k(const int* __restrict__ mask, unsigned long long* __restrict__ mp, int nwords) {
    int lane = threadIdx.x & 63;
    int gw = (blockIdx.x * blockDim.x + threadIdx.x) >> 6;
    int nw = (gridDim.x * blockDim.x) >> 6;
    for (int w = gw; w < nwords; w += nw) {
        int v = mask[(size_t)w * 64 + lane];
        unsigned long long bits = __ballot(v != 0);
        if (lane == 0) mp[w] = bits;
    }
}

// ---------------- X fp32 -> f16 (same layout) ----------------
__global__ __launch_bounds__(256) void cvt_x_k(const float* __restrict__ xq, const float* __restrict__ xk,
                                               const float* __restrict__ xv, f16* __restrict__ oq,
                                               f16* __restrict__ ok, f16* __restrict__ ov) {
    const float* src = blockIdx.z == 0 ? xq : (blockIdx.z == 1 ? xk : xv);
    f16* dst = blockIdx.z == 0 ? oq : (blockIdx.z == 1 ? ok : ov);
    size_t i = ((size_t)blockIdx.x * 256 + threadIdx.x) * 8;
    float4 a = *(const float4*)&src[i];
    float4 b = *(const float4*)&src[i + 4];
    f16x8 h;
    h[0] = (f16)a.x; h[1] = (f16)a.y; h[2] = (f16)a.z; h[3] = (f16)a.w;
    h[4] = (f16)b.x; h[5] = (f16)b.y; h[6] = (f16)b.z; h[7] = (f16)b.w;
    *(f16x8*)&dst[i] = h;
}

// ---------------- W fp32 [K][N] -> Wt f16 [N][K] (4 matrices via z) ----------------
__global__ __launch_bounds__(256) void wt_k(const float* __restrict__ Wq, const float* __restrict__ Wk,
                                            const float* __restrict__ Wv, const float* __restrict__ Wo,
                                            f16* __restrict__ Wt) {
    __shared__ float T[64][65];
    const int z = blockIdx.z;
    const float* W = z == 0 ? Wq : (z == 1 ? Wk : (z == 2 ? Wv : Wo));
    f16* out = Wt + (size_t)z * DM * DM;
    const int k0 = blockIdx.y * 64, n0 = blockIdx.x * 64;
    const int r = threadIdx.x >> 2, q = threadIdx.x & 3;
    const float4* s = (const float4*)&W[(size_t)(k0 + r) * DM + n0 + q * 16];
    float4 v0 = s[0], v1 = s[1], v2 = s[2], v3 = s[3];
    T[r][q * 16 + 0] = v0.x; T[r][q * 16 + 1] = v0.y; T[r][q * 16 + 2] = v0.z; T[r][q * 16 + 3] = v0.w;
    T[r][q * 16 + 4] = v1.x; T[r][q * 16 + 5] = v1.y; T[r][q * 16 + 6] = v1.z; T[r][q * 16 + 7] = v1.w;
    T[r][q * 16 + 8] = v2.x; T[r][q * 16 + 9] = v2.y; T[r][q * 16 + 10] = v2.z; T[r][q * 16 + 11] = v2.w;
    T[r][q * 16 + 12] = v3.x; T[r][q * 16 + 13] = v3.y; T[r][q * 16 + 14] = v3.z; T[r][q * 16 + 15] = v3.w;
    __syncthreads();
    f16x8 h0, h1;
#pragma unroll
    for (int j = 0; j < 8; ++j) {
        h0[j] = (f16)T[q * 16 + j][r];
        h1[j] = (f16)T[q * 16 + 8 + j][r];
    }
    *(f16x8*)&out[(size_t)(n0 + r) * DM + k0 + q * 16] = h0;
    *(f16x8*)&out[(size_t)(n0 + r) * DM + k0 + q * 16 + 8] = h1;
}

// ---------------- f16 GEMM core: C[128x128] = A[128xK] . Bt[128xK]^T, K=1024 ----------------
// LDS linear [row][8 chunks of 16B]; source-side XOR swizzle cc^=(row&7), same XOR on frag reads.
__device__ __forceinline__ void gemm_core(const f16* __restrict__ A, const f16* __restrict__ Bt,
                                          int m0, int n0, f16* Al, f16* Bl, f32x4 acc[4][4], int tid) {
    const int lane = tid & 63;
    const int wv = tid >> 6;
    const int wr = wv >> 1, wc = wv & 1;
    const int g = lane >> 4, c = lane & 15;

    for (int k0 = 0; k0 < DM; k0 += 64) {
#pragma unroll
        for (int j = 0; j < 4; ++j) {
            int chunk = j * 256 + tid;  // 0..1023
            int row = chunk >> 3, cc = chunk & 7;
            int ccs = cc ^ (row & 7);
            GLDS(&A[(size_t)(m0 + row) * DM + k0 + ccs * 8], &Al[chunk * 8]);
        }
#pragma unroll
        for (int j = 0; j < 4; ++j) {
            int chunk = j * 256 + tid;
            int row = chunk >> 3, cc = chunk & 7;
            int ccs = cc ^ (row & 7);
            GLDS(&Bt[(size_t)(n0 + row) * DM + k0 + ccs * 8], &Bl[chunk * 8]);
        }
        __syncthreads();  // compiler drains vmcnt(0): tile staged
#pragma unroll
        for (int ks = 0; ks < 2; ++ks) {
            f16x8 af[4], bf[4];
#pragma unroll
            for (int mi = 0; mi < 4; ++mi) {
                int row = wr * 64 + mi * 16 + c;
                af[mi] = *(const f16x8*)&Al[row * 64 + ((ks * 4 + g) ^ (row & 7)) * 8];
            }
#pragma unroll
            for (int ni = 0; ni < 4; ++ni) {
                int row = wc * 64 + ni * 16 + c;
                bf[ni] = *(const f16x8*)&Bl[row * 64 + ((ks * 4 + g) ^ (row & 7)) * 8];
            }
#pragma unroll
            for (int mi = 0; mi < 4; ++mi)
#pragma unroll
                for (int ni = 0; ni < 4; ++ni)
                    acc[mi][ni] = MFMA16(af[mi], bf[ni], acc[mi][ni]);
        }
        __syncthreads();  // frag reads done before next stage overwrites
    }
}

// ---------------- QKV projection: f16 Xh . Wt + b -> f16 per-head [B,H,S,DK] ----------------
__global__ __launch_bounds__(256) void gemm_qkv2_k(
    const f16* __restrict__ Xq, const f16* __restrict__ Xk, const f16* __restrict__ Xv,
    const f16* __restrict__ Wt, const float* __restrict__ bq, const float* __restrict__ bk,
    const float* __restrict__ bv, f16* __restrict__ Qh, f16* __restrict__ Kh, f16* __restrict__ Vh) {
    __shared__ f16 Al[128 * 64];
    __shared__ f16 Bl[128 * 64];
    const int which = blockIdx.z;
    const f16* A = which == 0 ? Xq : (which == 1 ? Xk : Xv);
    const f16* Bt = Wt + (size_t)which * DM * DM;
    const float* bias = which == 0 ? bq : (which == 1 ? bk : bv);
    f16* OUT = which == 0 ? Qh : (which == 1 ? Kh : Vh);

    const int tid = threadIdx.x, lane = tid & 63, wv = tid >> 6;
    const int wr = wv >> 1, wc = wv & 1, g = lane >> 4, c = lane & 15;
    const int m0 = blockIdx.y * 128, n0 = blockIdx.x * 128;

    f32x4 acc[4][4] = {};
    gemm_core(A, Bt, m0, n0, Al, Bl, acc, tid);

#pragma unroll
    for (int ni = 0; ni < 4; ++ni) {
        int n = n0 + wc * 64 + ni * 16 + c;
        float bias_n = bias[n];
        int hh = n >> 6, d = n & 63;
#pragma unroll
        for (int mi = 0; mi < 4; ++mi) {
            int mbase = m0 + wr * 64 + mi * 16 + g * 4;
#pragma unroll
            for (int r = 0; r < 4; ++r) {
                int m = mbase + r;
                int bb = m >> 11, s = m & (SEQ - 1);
                OUT[(((size_t)(bb * NHEAD + hh)) * SEQ + s) * DK + d] = (f16)(acc[mi][ni][r] + bias_n);
            }
        }
    }
}

// ---------------- output projection: f16 Xo . Wto + bo -> fp32 [M][DM] ----------------
__global__ __launch_bounds__(256) void gemm_out2_k(
    const f16* __restrict__ Xo, const f16* __restrict__ Wto, const float* __restrict__ bo,
    float* __restrict__ OUT) {
    __shared__ f16 Al[128 * 64];
    __shared__ f16 Bl[128 * 64];
    const int tid = threadIdx.x, lane = tid & 63, wv = tid >> 6;
    const int wr = wv >> 1, wc = wv & 1, g = lane >> 4, c = lane & 15;
    const int m0 = blockIdx.y * 128, n0 = blockIdx.x * 128;

    f32x4 acc[4][4] = {};
    gemm_core(Xo, Wto, m0, n0, Al, Bl, acc, tid);

#pragma unroll
    for (int ni = 0; ni < 4; ++ni) {
        int n = n0 + wc * 64 + ni * 16 + c;
        float bias_n = bo[n];
#pragma unroll
        for (int mi = 0; mi < 4; ++mi) {
            int mbase = m0 + wr * 64 + mi * 16 + g * 4;
#pragma unroll
            for (int r = 0; r < 4; ++r) {
                int m = mbase + r;
                OUT[(size_t)m * DM + n] = acc[mi][ni][r] + bias_n;
            }
        }
    }
}

// ---------------- flash attention (swapped-operand), QBLK=128 ----------------
#define SW(r, z) (((z) ^ ((r) & 7) ^ (((r) >> 3) & 7)))
#define QBLK 128
#define CSC 0.18033688011112042f /* 0.125 * log2(e) */

__global__ __launch_bounds__(256, 2) void attn_k(
    const f16* __restrict__ Qh, const f16* __restrict__ Kh, const f16* __restrict__ Vh,
    const unsigned long long* __restrict__ mp, f16* __restrict__ Xo) {
    __shared__ f16 Klds[2][4096]; // [key][d], swizzled chunks
    __shared__ f16 Vt[2][4096];   // [d][key], swizzled chunks
    __shared__ f16 Plds[4][16 * 72];

    const int tid = threadIdx.x, lane = tid & 63, wv = tid >> 6;
    const int g = lane >> 4, c = lane & 15;
    const int qt = blockIdx.x, hh = blockIdx.y, b = blockIdx.z;
    const size_t headoff = ((size_t)(b * NHEAD + hh)) * SEQ * DK;
    const f16* Qb = Qh + headoff;
    const f16* Kb = Kh + headoff;
    const f16* Vb = Vh + headoff;

    int qrow[2];
    f16x8 bq[2][2];
#pragma unroll
    for (int qg = 0; qg < 2; ++qg) {
        qrow[qg] = qt * QBLK + wv * 32 + qg * 16 + c;
        bq[qg][0] = *(const f16x8*)&Qb[(size_t)qrow[qg] * DK + g * 8];
        bq[qg][1] = *(const f16x8*)&Qb[(size_t)qrow[qg] * DK + 32 + g * 8];
    }

    f32x4 acc[2][4] = {};
    float m_run[2] = {-3e38f, -3e38f}, l_run[2] = {0.f, 0.f};

    const int krow = tid >> 2, kseg = tid & 3;

    f16x8 ck0, ck1, cv0, cv1;
    {
        const f16x8* ks_ = (const f16x8*)&Kb[(size_t)krow * DK + kseg * 16];
        ck0 = ks_[0]; ck1 = ks_[1];
        const f16x8* vs_ = (const f16x8*)&Vb[(size_t)krow * DK + kseg * 16];
        cv0 = vs_[0]; cv1 = vs_[1];
    }
    *(f16x8*)&Klds[0][krow * 64 + SW(krow, kseg * 2) * 8] = ck0;
    *(f16x8*)&Klds[0][krow * 64 + SW(krow, kseg * 2 + 1) * 8] = ck1;
#pragma unroll
    for (int i = 0; i < 8; ++i) {
        int d0 = kseg * 16 + i, d1 = d0 + 8;
        Vt[0][d0 * 64 + SW(d0, krow >> 3) * 8 + (krow & 7)] = cv0[i];
        Vt[0][d1 * 64 + SW(d1, krow >> 3) * 8 + (krow & 7)] = cv1[i];
    }
    {
        const f16x8* ks_ = (const f16x8*)&Kb[(size_t)(64 + krow) * DK + kseg * 16];
        ck0 = ks_[0]; ck1 = ks_[1];
        const f16x8* vs_ = (const f16x8*)&Vb[(size_t)(64 + krow) * DK + kseg * 16];
        cv0 = vs_[0]; cv1 = vs_[1];
    }

    int p = 0;
    for (int kt = 0; kt < SEQ / 64; ++kt) {
        __syncthreads();

        f16x8 ak[4][2], av[4][2];
#pragma unroll
        for (int nk = 0; nk < 4; ++nk) {
            int row = nk * 16 + c;
#pragma unroll
            for (int ks = 0; ks < 2; ++ks)
                ak[nk][ks] = *(const f16x8*)&Klds[p][row * 64 + SW(row, ks * 4 + g) * 8];
        }
#pragma unroll
        for (int nd = 0; nd < 4; ++nd) {
            int row = nd * 16 + c;
#pragma unroll
            for (int ks = 0; ks < 2; ++ks)
                av[nd][ks] = *(const f16x8*)&Vt[p][row * 64 + SW(row, ks * 4 + g) * 8];
        }

        if (kt + 1 < SEQ / 64) {
            *(f16x8*)&Klds[p ^ 1][krow * 64 + SW(krow, kseg * 2) * 8] = ck0;
            *(f16x8*)&Klds[p ^ 1][krow * 64 + SW(krow, kseg * 2 + 1) * 8] = ck1;
#pragma unroll
            for (int i = 0; i < 8; ++i) {
                int d0 = kseg * 16 + i, d1 = d0 + 8;
                Vt[p ^ 1][d0 * 64 + SW(d0, krow >> 3) * 8 + (krow & 7)] = cv0[i];
                Vt[p ^ 1][d1 * 64 + SW(d1, krow >> 3) * 8 + (krow & 7)] = cv1[i];
            }
            if (kt + 2 < SEQ / 64) {
                const f16x8* ks_ = (const f16x8*)&Kb[(size_t)((kt + 2) * 64 + krow) * DK + kseg * 16];
                ck0 = ks_[0]; ck1 = ks_[1];
                const f16x8* vs_ = (const f16x8*)&Vb[(size_t)((kt + 2) * 64 + krow) * DK + kseg * 16];
                cv0 = vs_[0]; cv1 = vs_[1];
            }
        }

#pragma unroll
        for (int qg = 0; qg < 2; ++qg) {
            f32x4 sc[4];
#pragma unroll
            for (int nk = 0; nk < 4; ++nk) {
                f32x4 z = {};
                z = MFMA16(ak[nk][0], bq[qg][0], z);
                z = MFMA16(ak[nk][1], bq[qg][1], z);
                sc[nk] = z;
            }
            unsigned long long wq = mp[((size_t)b * SEQ + qrow[qg]) * (SEQ / 64) + kt] >> (g * 4);
            float pm = -3e38f;
#pragma unroll
            for (int nk = 0; nk < 4; ++nk)
#pragma unroll
                for (int r = 0; r < 4; ++r) {
                    float sv = ((wq >> (nk * 16 + r)) & 1ull) ? sc[nk][r] * CSC : -1.0e9f;
                    sc[nk][r] = sv;
                    pm = fmaxf(pm, sv);
                }
            pm = fmaxf(pm, __shfl_xor(pm, 16));
            pm = fmaxf(pm, __shfl_xor(pm, 32));
            float mn = fmaxf(m_run[qg], pm);
            float corr = exp2f(m_run[qg] - mn);
            m_run[qg] = mn;
            float ps = 0.f;
#pragma unroll
            for (int nk = 0; nk < 4; ++nk)
#pragma unroll
                for (int r = 0; r < 4; ++r) {
                    float pp = exp2f(sc[nk][r] - mn);
                    sc[nk][r] = pp;
                    ps += pp;
                }
            ps += __shfl_xor(ps, 16);
            ps += __shfl_xor(ps, 32);
            l_run[qg] = l_run[qg] * corr + ps;
#pragma unroll
            for (int nd = 0; nd < 4; ++nd)
#pragma unroll
                for (int r = 0; r < 4; ++r) acc[qg][nd][r] *= corr;

#pragma unroll
            for (int nk = 0; nk < 4; ++nk)
#pragma unroll
                for (int r2 = 0; r2 < 2; ++r2) {
                    f16x2 pw = {(f16)sc[nk][r2 * 2], (f16)sc[nk][r2 * 2 + 1]};
                    *(f16x2*)&Plds[wv][c * 72 + nk * 16 + g * 4 + r2 * 2] = pw;
                }
            f16x8 pb0 = *(const f16x8*)&Plds[wv][c * 72 + g * 8];
            f16x8 pb1 = *(const f16x8*)&Plds[wv][c * 72 + 32 + g * 8];
#pragma unroll
            for (int nd = 0; nd < 4; ++nd) {
                acc[qg][nd] = MFMA16(av[nd][0], pb0, acc[qg][nd]);
                acc[qg][nd] = MFMA16(av[nd][1], pb1, acc[qg][nd]);
            }
        }
        p ^= 1;
    }

#pragma unroll
    for (int qg = 0; qg < 2; ++qg) {
        float inv = 1.0f / l_run[qg];
#pragma unroll
        for (int nd = 0; nd < 4; ++nd) {
            f16x4 o;
#pragma unroll
            for (int r = 0; r < 4; ++r) o[r] = (f16)(acc[qg][nd][r] * inv);
            *(f16x4*)&Xo[((size_t)(b * SEQ) + qrow[qg]) * DM + hh * DK + nd * 16 + g * 4] = o;
        }
    }
}

extern "C" void kernel_launch(void* const* d_in, const int* in_sizes, int n_in,
                              void* d_out, int out_size, void* d_ws, size_t ws_size,
                              hipStream_t stream) {
    const float* query = (const float*)d_in[0];
    const float* key_ = (const float*)d_in[1];
    const float* value = (const float*)d_in[2];
    const int* mask = (const int*)d_in[3];
    const float* Wq = (const float*)d_in[4];
    const float* bq = (const float*)d_in[5];
    const float* Wk = (const float*)d_in[6];
    const float* bk = (const float*)d_in[7];
    const float* Wv = (const float*)d_in[8];
    const float* bv = (const float*)d_in[9];
    const float* Wo = (const float*)d_in[10];
    const float* bo = (const float*)d_in[11];
    float* out = (float*)d_out;

    // ws layout (57 MiB): mp(1M) | Qh(8M) | Kh(8M) | Vh(8M) | Xh_q/Xo(8M) | Xh_k(8M) | Xh_v(8M) | Wt(8M)
    char* ws = (char*)d_ws;
    const size_t headsz = (size_t)NBATCH * NHEAD * SEQ * DK * sizeof(f16); // 8 MiB
    unsigned long long* mp = (unsigned long long*)(ws);
    f16* Qh = (f16*)(ws + (1 << 20));
    f16* Kh = (f16*)(ws + (1 << 20) + headsz);
    f16* Vh = (f16*)(ws + (1 << 20) + 2 * headsz);
    f16* Xhq = (f16*)(ws + (1 << 20) + 3 * headsz); // aliased: Xo after gemm_qkv consumes Xhq
    f16* Xhk = (f16*)(ws + (1 << 20) + 4 * headsz);
    f16* Xhv = (f16*)(ws + (1 << 20) + 5 * headsz);
    f16* Wt = (f16*)(ws + (1 << 20) + 6 * headsz); // 4 x [1024][1024] f16
    f16* Xo = Xhq;

    int nwords = NBATCH * SEQ * (SEQ / 64);
    hipLaunchKernelGGL(pack_mask_k, dim3(512), dim3(256), 0, stream, mask, mp, nwords);
    hipLaunchKernelGGL(cvt_x_k, dim3(M_TOT * DM / (8 * 256), 1, 3), dim3(256), 0, stream,
                       query, key_, value, Xhq, Xhk, Xhv);
    hipLaunchKernelGGL(wt_k, dim3(DM / 64, DM / 64, 4), dim3(256), 0, stream, Wq, Wk, Wv, Wo, Wt);
    hipLaunchKernelGGL(gemm_qkv2_k, dim3(DM / 128, M_TOT / 128, 3), dim3(256), 0, stream,
                       Xhq, Xhk, Xhv, Wt, bq, bk, bv, Qh, Kh, Vh);
    hipLaunchKernelGGL(attn_k, dim3(SEQ / QBLK, NHEAD, NBATCH), dim3(256), 0, stream, Qh, Kh, Vh, mp, Xo);
    hipLaunchKernelGGL(gemm_out2_k, dim3(DM / 128, M_TOT / 128), dim3(256), 0, stream,
                       Xo, Wt + (size_t)3 * DM * DM, bo, out);
}